// Round 6
// baseline (456.662 us; speedup 1.0000x reference)
//
#include <hip/hip_runtime.h>
#include <hip/hip_cooperative_groups.h>
#include <cstdint>
#include <cstddef>

namespace cg = cooperative_groups;

#define NNODES 50000
#define NEDGES 800000
#define MEDGES (NEDGES + NNODES)
#define FIN    256
#define HID    96
#define NCLS   32
#define NEG_SLOPE 0.2f

#define NBUCK  391      // ceil(50000/128): 128-node dst ranges
#define BCAP   3072     // per-bucket staging capacity (mean 2176, sigma ~45)
#define NCHUNK ((MEDGES + 2047) / 2048)   // 416 bucket1 chunks
#define NGEMM1 ((NNODES + 63) / 64)       // 782 gemm1 units
#define NAGG   (NNODES / 8)               // 6250 agg units (exact)

typedef unsigned int uint32;
typedef __attribute__((ext_vector_type(8))) short short8;   // 8 bf16 = 4 VGPR
typedef __attribute__((ext_vector_type(4))) float f32x4;    // MFMA acc

__device__ __forceinline__ ushort bf_round(float f) {
    uint32 u = __float_as_uint(f);
    u += 0x7FFFu + ((u >> 16) & 1u);            // RNE
    return (ushort)(u >> 16);
}
__device__ __forceinline__ uint32 pack_bf16x2(float a, float b) {
    return (uint32)bf_round(a) | ((uint32)bf_round(b) << 16);
}
__device__ __forceinline__ float bf_lo(uint32 u) { return __uint_as_float(u << 16); }
__device__ __forceinline__ float bf_hi(uint32 u) { return __uint_as_float(u & 0xFFFF0000u); }
__device__ __forceinline__ float lrelu(float t) { return (t > 0.f) ? t : NEG_SLOPE * t; }
__device__ __forceinline__ float af(int i) { return __int_as_float(i); }
__device__ __forceinline__ float elu_fast(float t) { return (t > 0.f) ? t : (__expf(t) - 1.f); }

// Shared-memory union across phases (max = phase-3: 17408 B)
struct __align__(16) SU {
    union {
        struct { int hist[NBUCK]; int base_sh[NBUCK]; } s1;                       // bucket1
        struct { int dcount[128]; int dincl[128]; int dexcl[128];
                 int fillc[128]; int red_s[256]; } s2;                            // bucket2
        struct { int2 sa[4][2][32]; float W2n[96 * 32]; float y_sh[4][2][96]; } s3; // agg96+g2
        struct { int2 sa[4][2][32]; } s4;                                         // agg32
    } u;
};

// ---------------- ONE persistent cooperative kernel: 5 phases, 4 grid syncs ----------------
// Eliminates 4 launch gaps + tiny packw dispatch; W2 staged once per block for
// all its phase-3 grid-stride iterations. Phase bodies are the round-2-verified
// forms (fastest measured); agg96 epilogue uses the conflict-free W2n layout
// (0 bank conflicts, verified r4/r5). Scheduling tricks intentionally absent:
// 3 consecutive rounds proved source-level prefetch nulls here.

__global__ __launch_bounds__(256) void fused_all(
        const float* __restrict__ x,   const int* __restrict__ ei,
        const float* __restrict__ W1,
        const float* __restrict__ a1s, const float* __restrict__ a1d,
        const float* __restrict__ b1,
        const float* __restrict__ W2,
        const float* __restrict__ a2s, const float* __restrict__ a2d,
        const float* __restrict__ b2,
        float* __restrict__ out,
        ushort* __restrict__ h1, uint32* __restrict__ h2b,
        int* __restrict__ staging, float* __restrict__ as1, float* __restrict__ ad1,
        float* __restrict__ as2, float* __restrict__ ad2,
        int* __restrict__ rowptr, int* __restrict__ esrc,
        ushort* __restrict__ W1p, int* __restrict__ gcount) {
    __shared__ SU sh;
    cg::grid_group grid = cg::this_grid();

    const int t    = threadIdx.x;
    const int wave = t >> 6;
    const int lane = t & 63;
    const int hf   = lane >> 5;
    const int fl32 = lane & 31;

    // ---------------- phase 0: W1 pack + gcount zero ----------------
    {
        int stride = gridDim.x * 256;
        int tid0 = blockIdx.x * 256 + t;
        for (int idx = tid0; idx < NBUCK; idx += stride) gcount[idx] = 0;
        for (int idx = tid0; idx < 6 * 8 * 64 * 8; idx += stride) {
            int j     = idx & 7;
            int ln    = (idx >> 3) & 63;
            int kstep = (idx >> 9) & 7;
            int ntile = idx >> 12;
            int k = kstep * 32 + ((ln >> 4) << 3) + j;
            int n = ntile * 16 + (ln & 15);
            W1p[idx] = bf_round(W1[(size_t)k * 96 + n]);
        }
    }
    grid.sync();

    // ---------------- phase 1: bucket1 (CSR staging) ----------------
    for (int chunk = blockIdx.x; chunk < NCHUNK; chunk += gridDim.x) {
        for (int i = t; i < NBUCK; i += 256) sh.u.s1.hist[i] = 0;
        __syncthreads();
        int v[8], rk[8], bk[8];
        int e0 = chunk * 2048;
#pragma unroll
        for (int i = 0; i < 8; ++i) {
            int e = e0 + i * 256 + t;
            if (e < MEDGES) {
                int s, d;
                if (e < NEDGES) { s = ei[e]; d = ei[NEDGES + e]; }
                else            { s = e - NEDGES; d = s; }
                bk[i] = d >> 7;
                v[i]  = s | ((d & 127) << 16);
                rk[i] = atomicAdd(&sh.u.s1.hist[bk[i]], 1);
            } else bk[i] = -1;
        }
        __syncthreads();
        for (int i = t; i < NBUCK; i += 256) {
            int c = sh.u.s1.hist[i];
            sh.u.s1.base_sh[i] = c ? atomicAdd(&gcount[i], c) : 0;
        }
        __syncthreads();
#pragma unroll
        for (int i = 0; i < 8; ++i) {
            if (bk[i] >= 0) {
                int pos = sh.u.s1.base_sh[bk[i]] + rk[i];
                if (pos < BCAP)
                    staging[(size_t)bk[i] * BCAP + pos] = v[i];
            }
        }
        __syncthreads();
    }
    grid.sync();

    // ---------------- phase 2: bucket2 (units 0..390) || gemm1 (units 391..1172) ----------------
    for (int uu = blockIdx.x; uu < NBUCK + NGEMM1; uu += gridDim.x) {
        if (uu < NBUCK) {
            const int b = uu;
            int pv = 0;
            for (int idx = t; idx < b; idx += 256) pv += gcount[idx];
            sh.u.s2.red_s[t] = pv;
            __syncthreads();
            for (int off2 = 128; off2; off2 >>= 1) {
                if (t < off2) sh.u.s2.red_s[t] += sh.u.s2.red_s[t + off2];
                __syncthreads();
            }
            const int ebase = sh.u.s2.red_s[0];
            const int cnt   = gcount[b];
            const int node0 = b << 7;
            const int* st   = staging + (size_t)b * BCAP;

            for (int i = t; i < 128; i += 256) { sh.u.s2.dcount[i] = 0; sh.u.s2.fillc[i] = 0; }
            __syncthreads();
            for (int i = t; i < cnt; i += 256)
                atomicAdd(&sh.u.s2.dcount[st[i] >> 16], 1);
            __syncthreads();
            if (t < 128) sh.u.s2.dincl[t] = sh.u.s2.dcount[t];
            __syncthreads();
            for (int off = 1; off < 128; off <<= 1) {
                int val = (t >= off && t < 128) ? sh.u.s2.dincl[t - off] : 0;
                __syncthreads();
                if (t < 128) sh.u.s2.dincl[t] += val;
                __syncthreads();
            }
            if (t < 128) {
                int excl = sh.u.s2.dincl[t] - sh.u.s2.dcount[t];
                sh.u.s2.dexcl[t] = excl;
                int node = node0 + t;
                if (node < NNODES) rowptr[node] = ebase + excl;
            }
            if (b == NBUCK - 1 && t == 0) rowptr[NNODES] = MEDGES;
            __syncthreads();
            for (int i = t; i < cnt; i += 256) {
                int v = st[i];
                int dd = v >> 16;
                int r = atomicAdd(&sh.u.s2.fillc[dd], 1);
                esrc[ebase + sh.u.s2.dexcl[dd] + r] = v & 0xFFFF;
            }
            __syncthreads();
        } else {
            // gemm1: h1(bf16) = x @ W1 (+ fused alpha dots)
            const int m    = lane & 15;
            const int quad = lane >> 4;
            const int node0 = (uu - NBUCK) * 64;

            int arow = node0 + wave * 16 + m;
            if (arow >= NNODES) arow = NNODES - 1;
            const float* xr = x + (size_t)arow * FIN + quad * 8;
            const short8* Wp = (const short8*)W1p;

            f32x4 acc[6];
#pragma unroll
            for (int tt = 0; tt < 6; ++tt) acc[tt] = (f32x4){0.f, 0.f, 0.f, 0.f};
#pragma unroll
            for (int ks = 0; ks < 8; ++ks) {
                float4 v0 = *(const float4*)(xr + ks * 32);
                float4 v1 = *(const float4*)(xr + ks * 32 + 4);
                short8 a;
                a[0] = (short)bf_round(v0.x); a[1] = (short)bf_round(v0.y);
                a[2] = (short)bf_round(v0.z); a[3] = (short)bf_round(v0.w);
                a[4] = (short)bf_round(v1.x); a[5] = (short)bf_round(v1.y);
                a[6] = (short)bf_round(v1.z); a[7] = (short)bf_round(v1.w);
#pragma unroll
                for (int tt = 0; tt < 6; ++tt) {
                    short8 bfr = Wp[(tt * 8 + ks) * 64 + lane];
                    acc[tt] = __builtin_amdgcn_mfma_f32_16x16x32_bf16(a, bfr, acc[tt], 0, 0, 0);
                }
            }

            float as_reg[6], ad_reg[6];
#pragma unroll
            for (int tt = 0; tt < 6; ++tt) {
                as_reg[tt] = a1s[tt * 16 + m];
                ad_reg[tt] = a1d[tt * 16 + m];
            }
#pragma unroll
            for (int r = 0; r < 4; ++r) {
                int node = node0 + wave * 16 + quad * 4 + r;
                float ps = 0.f, pd = 0.f;
#pragma unroll
                for (int tt = 0; tt < 6; ++tt) {
                    ps += acc[tt][r] * as_reg[tt];
                    pd += acc[tt][r] * ad_reg[tt];
                }
#pragma unroll
                for (int off = 1; off < 16; off <<= 1) {
                    ps += __shfl_xor(ps, off);
                    pd += __shfl_xor(pd, off);
                }
                if (node < NNODES) {
                    ushort* hp = h1 + (size_t)node * 96 + m;
#pragma unroll
                    for (int tt = 0; tt < 6; ++tt) hp[tt * 16] = bf_round(acc[tt][r]);
                    if (m == 0) { as1[node] = ps; ad1[node] = pd; }
                }
            }
        }
    }
    grid.sync();

    // ---------------- phase 3: agg96 + fused gemm2 epilogue (round-2 body, W2n epilogue) ----------------
    for (int idx = t; idx < 96 * 32; idx += 256)
        sh.u.s3.W2n[idx] = W2[idx];              // [k][c]: lane c -> bank c, conflict-free
    __syncthreads();
    {
        const float a2s_v = a2s[fl32];
        const float a2d_v = a2d[fl32];
        const int fl = (fl32 < 24) ? fl32 : 23;

        for (int uu = blockIdx.x; uu < NAGG; uu += gridDim.x) {
            const int i = uu * 8 + wave * 2 + hf;
            const int start = rowptr[i];
            const int deg   = rowptr[i + 1] - start;
            const float ad  = ad1[i];

            float acc0 = 0.f, acc1 = 0.f, acc2 = 0.f, acc3 = 0.f;

            if (deg <= 32) {
                bool valid = fl32 < deg;
                int s_reg = valid ? esrc[start + fl32] : 0;
                float e = valid ? lrelu(as1[s_reg] + ad) : -1e30f;
                float mx = e;
#pragma unroll
                for (int off = 16; off; off >>= 1) mx = fmaxf(mx, __shfl_xor(mx, off));
                float ex = valid ? __expf(e - mx) : 0.f;
                float sum = ex;
#pragma unroll
                for (int off = 16; off; off >>= 1) sum += __shfl_xor(sum, off);
                sh.u.s3.sa[wave][hf][fl32] = make_int2(s_reg, __float_as_int(ex / sum));

                const int4* sap = (const int4*)&sh.u.s3.sa[wave][hf][0];
                for (int eb = 0; eb < deg; eb += 8) {
                    int4 qa = sap[(eb >> 1) + 0];
                    int4 qb = sap[(eb >> 1) + 1];
                    int4 qc = sap[(eb >> 1) + 2];
                    int4 qd = sap[(eb >> 1) + 3];
                    const uint2* r0 = (const uint2*)(h1 + (size_t)qa.x * 96);
                    const uint2* r1 = (const uint2*)(h1 + (size_t)qa.z * 96);
                    const uint2* r2 = (const uint2*)(h1 + (size_t)qb.x * 96);
                    const uint2* r3 = (const uint2*)(h1 + (size_t)qb.z * 96);
                    const uint2* r4 = (const uint2*)(h1 + (size_t)qc.x * 96);
                    const uint2* r5 = (const uint2*)(h1 + (size_t)qc.z * 96);
                    const uint2* r6 = (const uint2*)(h1 + (size_t)qd.x * 96);
                    const uint2* r7 = (const uint2*)(h1 + (size_t)qd.z * 96);
                    uint2 u0 = r0[fl], u1 = r1[fl], u2 = r2[fl], u3 = r3[fl];
                    uint2 u4 = r4[fl], u5 = r5[fl], u6 = r6[fl], u7 = r7[fl];
                    float a0 = af(qa.y), a1 = af(qa.w), a2 = af(qb.y), a3 = af(qb.w);
                    float a4 = af(qc.y), a5 = af(qc.w), a6 = af(qd.y), a7 = af(qd.w);
                    acc0 += a0 * bf_lo(u0.x) + a1 * bf_lo(u1.x) + a2 * bf_lo(u2.x) + a3 * bf_lo(u3.x)
                          + a4 * bf_lo(u4.x) + a5 * bf_lo(u5.x) + a6 * bf_lo(u6.x) + a7 * bf_lo(u7.x);
                    acc1 += a0 * bf_hi(u0.x) + a1 * bf_hi(u1.x) + a2 * bf_hi(u2.x) + a3 * bf_hi(u3.x)
                          + a4 * bf_hi(u4.x) + a5 * bf_hi(u5.x) + a6 * bf_hi(u6.x) + a7 * bf_hi(u7.x);
                    acc2 += a0 * bf_lo(u0.y) + a1 * bf_lo(u1.y) + a2 * bf_lo(u2.y) + a3 * bf_lo(u3.y)
                          + a4 * bf_lo(u4.y) + a5 * bf_lo(u5.y) + a6 * bf_lo(u6.y) + a7 * bf_lo(u7.y);
                    acc3 += a0 * bf_hi(u0.y) + a1 * bf_hi(u1.y) + a2 * bf_hi(u2.y) + a3 * bf_hi(u3.y)
                          + a4 * bf_hi(u4.y) + a5 * bf_hi(u5.y) + a6 * bf_hi(u6.y) + a7 * bf_hi(u7.y);
                }
            } else {
                float mx = -1e30f;
                for (int p = start + fl32; p < start + deg; p += 32)
                    mx = fmaxf(mx, lrelu(as1[esrc[p]] + ad));
#pragma unroll
                for (int off = 16; off; off >>= 1) mx = fmaxf(mx, __shfl_xor(mx, off));
                float sum = 0.f;
                for (int p = start + fl32; p < start + deg; p += 32)
                    sum += __expf(lrelu(as1[esrc[p]] + ad) - mx);
#pragma unroll
                for (int off = 16; off; off >>= 1) sum += __shfl_xor(sum, off);
                float inv = 1.f / sum;
                for (int e = 0; e < deg; ++e) {
                    int s = esrc[start + e];
                    float a = __expf(lrelu(as1[s] + ad) - mx) * inv;
                    uint2 u = ((const uint2*)(h1 + (size_t)s * 96))[fl];
                    acc0 += a * bf_lo(u.x);
                    acc1 += a * bf_hi(u.x);
                    acc2 += a * bf_lo(u.y);
                    acc3 += a * bf_hi(u.y);
                }
            }

            // epilogue: bias + ELU -> y_sh, then fused h2 = y @ W2 (conflict-free W2n)
            if (fl32 < 24) {
                float* yp = &sh.u.s3.y_sh[wave][hf][4 * fl32];
                yp[0] = elu_fast(acc0 + b1[4 * fl32 + 0]);
                yp[1] = elu_fast(acc1 + b1[4 * fl32 + 1]);
                yp[2] = elu_fast(acc2 + b1[4 * fl32 + 2]);
                yp[3] = elu_fast(acc3 + b1[4 * fl32 + 3]);
            }
            asm volatile("s_waitcnt lgkmcnt(0)" ::: "memory");   // wave-internal y_sh visibility

            const float* yrow = &sh.u.s3.y_sh[wave][hf][0];
            float h2c = 0.f;
#pragma unroll
            for (int k4 = 0; k4 < 96; k4 += 4) {
                float4 yv = *(const float4*)(yrow + k4);           // broadcast within half
                h2c = fmaf(yv.x, sh.u.s3.W2n[(k4 + 0) * 32 + fl32], h2c);
                h2c = fmaf(yv.y, sh.u.s3.W2n[(k4 + 1) * 32 + fl32], h2c);
                h2c = fmaf(yv.z, sh.u.s3.W2n[(k4 + 2) * 32 + fl32], h2c);
                h2c = fmaf(yv.w, sh.u.s3.W2n[(k4 + 3) * 32 + fl32], h2c);
            }

            float ps = h2c * a2s_v;
            float pd = h2c * a2d_v;
#pragma unroll
            for (int off = 1; off < 32; off <<= 1) {
                ps += __shfl_xor(ps, off);
                pd += __shfl_xor(pd, off);
            }
            float partner = __shfl_xor(h2c, 16);                  // class c+16 for c<16
            if (fl32 < 16)
                h2b[(size_t)i * 16 + fl32] = pack_bf16x2(h2c, partner);
            if (fl32 == 0) { as2[i] = ps; ad2[i] = pd; }
        }
    }
    grid.sync();

    // ---------------- phase 4: agg32 + log_softmax ----------------
    {
        const int g  = fl32 >> 3;
        const int fl = fl32 & 7;
        for (int uu = blockIdx.x; uu < NAGG; uu += gridDim.x) {
            const int i = uu * 8 + wave * 2 + hf;
            const int start = rowptr[i];
            const int deg   = rowptr[i + 1] - start;
            const float ad  = ad2[i];

            float acc[4];
#pragma unroll
            for (int j = 0; j < 4; ++j) acc[j] = 0.f;

            if (deg <= 32) {
                bool valid = fl32 < deg;
                int s_reg = valid ? esrc[start + fl32] : 0;
                float e = valid ? lrelu(as2[s_reg] + ad) : -1e30f;
                float mx = e;
#pragma unroll
                for (int off = 16; off; off >>= 1) mx = fmaxf(mx, __shfl_xor(mx, off));
                float ex = valid ? __expf(e - mx) : 0.f;
                float sum = ex;
#pragma unroll
                for (int off = 16; off; off >>= 1) sum += __shfl_xor(sum, off);
                sh.u.s4.sa[wave][hf][fl32] = make_int2(s_reg, __float_as_int(ex / sum));

#pragma unroll 2
                for (int eb = 0; eb < deg; eb += 4) {
                    int e0 = eb + g;
                    int2 q = sh.u.s4.sa[wave][hf][(e0 < 32) ? e0 : 31];
                    float a = (e0 < deg) ? af(q.y) : 0.f;
                    const uint2* hr = (const uint2*)(h2b + (size_t)q.x * 16);
                    uint2 u = hr[fl];
                    acc[0] = fmaf(a, bf_lo(u.x), acc[0]);
                    acc[1] = fmaf(a, bf_hi(u.x), acc[1]);
                    acc[2] = fmaf(a, bf_lo(u.y), acc[2]);
                    acc[3] = fmaf(a, bf_hi(u.y), acc[3]);
                }
            } else {
                float mx = -1e30f;
                for (int p = start + fl32; p < start + deg; p += 32)
                    mx = fmaxf(mx, lrelu(as2[esrc[p]] + ad));
#pragma unroll
                for (int off = 16; off; off >>= 1) mx = fmaxf(mx, __shfl_xor(mx, off));
                float sum = 0.f;
                for (int p = start + fl32; p < start + deg; p += 32)
                    sum += __expf(lrelu(as2[esrc[p]] + ad) - mx);
#pragma unroll
                for (int off = 16; off; off >>= 1) sum += __shfl_xor(sum, off);
                float inv = 1.f / sum;
                for (int p = start + g; p < start + deg; p += 4) {
                    int s = esrc[p];
                    float a = __expf(lrelu(as2[s] + ad) - mx) * inv;
                    const uint2* hr = (const uint2*)(h2b + (size_t)s * 16);
                    uint2 u = hr[fl];
                    acc[0] = fmaf(a, bf_lo(u.x), acc[0]);
                    acc[1] = fmaf(a, bf_hi(u.x), acc[1]);
                    acc[2] = fmaf(a, bf_lo(u.y), acc[2]);
                    acc[3] = fmaf(a, bf_hi(u.y), acc[3]);
                }
            }

#pragma unroll
            for (int j = 0; j < 4; ++j) {
                acc[j] += __shfl_xor(acc[j], 8);
                acc[j] += __shfl_xor(acc[j], 16);
            }

            float z0 = acc[0] + b2[2 * fl];
            float z1 = acc[1] + b2[2 * fl + 16];
            float z2 = acc[2] + b2[2 * fl + 1];
            float z3 = acc[3] + b2[2 * fl + 17];
            float m2 = fmaxf(fmaxf(z0, z1), fmaxf(z2, z3));
#pragma unroll
            for (int off = 4; off; off >>= 1) m2 = fmaxf(m2, __shfl_xor(m2, off));
            float s2 = __expf(z0 - m2) + __expf(z1 - m2) + __expf(z2 - m2) + __expf(z3 - m2);
#pragma unroll
            for (int off = 4; off; off >>= 1) s2 += __shfl_xor(s2, off);
            float ls = m2 + __logf(s2);
            if (fl32 < 8) {
                float* op = out + (size_t)i * 32;
                op[2 * fl]      = z0 - ls;
                op[2 * fl + 16] = z1 - ls;
                op[2 * fl + 1]  = z2 - ls;
                op[2 * fl + 17] = z3 - ls;
            }
        }
    }
}

// ---------------- launch ----------------

extern "C" void kernel_launch(void* const* d_in, const int* in_sizes, int n_in,
                              void* d_out, int out_size, void* d_ws, size_t ws_size,
                              hipStream_t stream) {
    const float* x   = (const float*)d_in[0];
    const int*   ei  = (const int*)d_in[1];
    const float* W1  = (const float*)d_in[2];
    const float* a1s = (const float*)d_in[3];
    const float* a1d = (const float*)d_in[4];
    const float* b1  = (const float*)d_in[5];
    const float* W2  = (const float*)d_in[6];
    const float* a2s = (const float*)d_in[7];
    const float* a2d = (const float*)d_in[8];
    const float* b2  = (const float*)d_in[9];
    float* out = (float*)d_out;

    size_t off = 0;
    auto alloc = [&](size_t bytes) {
        void* p = (char*)d_ws + off;
        off += (bytes + 255) & ~(size_t)255;
        return p;
    };
    ushort* h1    = (ushort*)alloc((size_t)NNODES * HID * 2);   // bf16, 9.6 MB
    uint32* h2b   = (uint32*)alloc((size_t)NNODES * 16 * 4);    // bf16x2, 3.2 MB
    int*  staging = (int*)alloc((size_t)NBUCK * BCAP * 4);      // 4.8 MB
    float* as1    = (float*)alloc((size_t)NNODES * 4);
    float* ad1    = (float*)alloc((size_t)NNODES * 4);
    float* as2    = (float*)alloc((size_t)NNODES * 4);
    float* ad2    = (float*)alloc((size_t)NNODES * 4);
    int*   rowptr = (int*)alloc((size_t)(NNODES + 1) * 4);
    int*   esrc   = (int*)alloc((size_t)MEDGES * 4);
    ushort* W1p   = (ushort*)alloc((size_t)6 * 8 * 64 * 8 * 2); // 48 KiB
    int*   gcount = (int*)alloc((size_t)NBUCK * 4);

    // Cooperative grid: co-resident capacity (queried once, cached).
    static int g_grid = 0;
    if (g_grid == 0) {
        hipDeviceProp_t prop;
        hipGetDeviceProperties(&prop, 0);
        int nb = 0;
        hipOccupancyMaxActiveBlocksPerMultiprocessor(&nb, fused_all, 256, 0);
        if (nb < 1) nb = 1;
        long long g = (long long)prop.multiProcessorCount * nb;
        if (g > 4096) g = 4096;
        if (g < 1) g = 1;
        g_grid = (int)g;
    }

    void* args[] = { (void*)&x, (void*)&ei, (void*)&W1, (void*)&a1s, (void*)&a1d,
                     (void*)&b1, (void*)&W2, (void*)&a2s, (void*)&a2d, (void*)&b2,
                     (void*)&out, (void*)&h1, (void*)&h2b, (void*)&staging,
                     (void*)&as1, (void*)&ad1, (void*)&as2, (void*)&ad2,
                     (void*)&rowptr, (void*)&esrc, (void*)&W1p, (void*)&gcount };
    hipLaunchCooperativeKernel(fused_all, dim3(g_grid), dim3(256), args, 0, stream);
}

// Round 7
// 207.605 us; speedup vs baseline: 2.1997x; 2.1997x over previous
//
#include <hip/hip_runtime.h>
#include <cstdint>
#include <cstddef>

#define NNODES 50000
#define NEDGES 800000
#define MEDGES (NEDGES + NNODES)
#define FIN    256
#define HID    96
#define NCLS   32
#define NEG_SLOPE 0.2f

#define NBUCK  391      // ceil(50000/128): 128-node dst ranges
#define BCAP   3072     // per-bucket staging capacity (mean 2176, sigma ~45)

typedef unsigned int uint32;
typedef __attribute__((ext_vector_type(4))) float f32x4;        // MFMA acc
typedef _Float16 half2_t __attribute__((ext_vector_type(2)));   // v_pk_* operand
typedef _Float16 half8_t __attribute__((ext_vector_type(8)));   // MFMA f16 A/B frag

__device__ __forceinline__ half2_t u2h2(uint32 u) {
    union { uint32 u; half2_t h; } c; c.u = u; return c.h;
}
__device__ __forceinline__ uint32 h22u(half2_t h) {
    union { uint32 u; half2_t h; } c; c.h = h; return c.u;
}
__device__ __forceinline__ half2_t bc2(float a) {        // broadcast f32 -> (h,h)
    _Float16 x = (_Float16)a; half2_t r = {x, x}; return r;
}
__device__ __forceinline__ uint32 pack_h2(float a, float b) {
    half2_t r = {(_Float16)a, (_Float16)b}; return h22u(r);
}
__device__ __forceinline__ float lrelu(float t) { return (t > 0.f) ? t : NEG_SLOPE * t; }
__device__ __forceinline__ float elu_fast(float t) { return (t > 0.f) ? t : (__expf(t) - 1.f); }

// ---------------- W1-pack (fp16) + gcount zero (must precede bucket1's atomics) ----------------

__global__ __launch_bounds__(256) void packw_kernel(const float* __restrict__ W1,
                                                    _Float16* __restrict__ W1p,
                                                    int* __restrict__ gcount) {
    int stride = gridDim.x * 256;
    for (int idx = blockIdx.x * 256 + threadIdx.x; idx < NBUCK; idx += stride)
        gcount[idx] = 0;
    for (int idx = blockIdx.x * 256 + threadIdx.x; idx < 6 * 8 * 64 * 8; idx += stride) {
        int j     = idx & 7;
        int lane  = (idx >> 3) & 63;
        int kstep = (idx >> 9) & 7;
        int ntile = idx >> 12;
        int k = kstep * 32 + ((lane >> 4) << 3) + j;
        int n = ntile * 16 + (lane & 15);
        W1p[idx] = (_Float16)W1[(size_t)k * 96 + n];
    }
}

// ---------------- CSR build pass 1: bucketed staging ----------------
// staging entry packed: src (16 bits, 50000<65536) | (dst&127)<<16.

__global__ __launch_bounds__(256) void bucket1_kernel(const int* __restrict__ ei,
                                                      int* __restrict__ gcount,
                                                      int* __restrict__ staging) {
    __shared__ int hist[NBUCK];
    __shared__ int base_sh[NBUCK];
    for (int i = threadIdx.x; i < NBUCK; i += 256) hist[i] = 0;
    __syncthreads();

    int v[8], rk[8], bk[8];
    int e0 = blockIdx.x * 2048;
#pragma unroll
    for (int i = 0; i < 8; ++i) {
        int e = e0 + i * 256 + threadIdx.x;
        if (e < MEDGES) {
            int s, d;
            if (e < NEDGES) { s = ei[e]; d = ei[NEDGES + e]; }
            else            { s = e - NEDGES; d = s; }
            bk[i] = d >> 7;
            v[i]  = s | ((d & 127) << 16);
            rk[i] = atomicAdd(&hist[bk[i]], 1);
        } else bk[i] = -1;
    }
    __syncthreads();
    for (int i = threadIdx.x; i < NBUCK; i += 256) {
        int c = hist[i];
        base_sh[i] = c ? atomicAdd(&gcount[i], c) : 0;
    }
    __syncthreads();
#pragma unroll
    for (int i = 0; i < 8; ++i) {
        if (bk[i] >= 0) {
            int pos = base_sh[bk[i]] + rk[i];
            if (pos < BCAP)
                staging[(size_t)bk[i] * BCAP + pos] = v[i];
        }
    }
}

// ---------------- merged dispatch: bucket2 (blocks 0..390) + gemm1 (391..1172) ----------------

__global__ __launch_bounds__(256) void b2gemm1_kernel(const int* __restrict__ staging,
                                                      const int* __restrict__ gcount,
                                                      int* __restrict__ rowptr,
                                                      int* __restrict__ esrc,
                                                      const float* __restrict__ x,
                                                      const _Float16* __restrict__ W1p,
                                                      const float* __restrict__ a_src,
                                                      const float* __restrict__ a_dst,
                                                      _Float16* __restrict__ h1,
                                                      float* __restrict__ as1,
                                                      float* __restrict__ ad1) {
    __shared__ int dcount[128];
    __shared__ int dincl[128];
    __shared__ int dexcl[128];
    __shared__ int fillc[128];
    __shared__ int red_s[256];

    if (blockIdx.x < NBUCK) {
        // ---- bucket2: rowptr + esrc build for bucket b ----
        const int b = blockIdx.x;
        const int t = threadIdx.x;

        int pv = 0;
        for (int idx = t; idx < b; idx += 256) pv += gcount[idx];
        red_s[t] = pv;
        __syncthreads();
        for (int off2 = 128; off2; off2 >>= 1) {
            if (t < off2) red_s[t] += red_s[t + off2];
            __syncthreads();
        }
        const int ebase = red_s[0];
        const int cnt   = gcount[b];
        const int node0 = b << 7;
        const int* st   = staging + (size_t)b * BCAP;

        for (int i = t; i < 128; i += 256) { dcount[i] = 0; fillc[i] = 0; }
        __syncthreads();

        for (int i = t; i < cnt; i += 256)
            atomicAdd(&dcount[st[i] >> 16], 1);
        __syncthreads();

        if (t < 128) dincl[t] = dcount[t];
        __syncthreads();
        for (int off = 1; off < 128; off <<= 1) {
            int val = (t >= off && t < 128) ? dincl[t - off] : 0;
            __syncthreads();
            if (t < 128) dincl[t] += val;
            __syncthreads();
        }
        if (t < 128) {
            int excl = dincl[t] - dcount[t];
            dexcl[t] = excl;
            int node = node0 + t;
            if (node < NNODES) rowptr[node] = ebase + excl;
        }
        if (b == NBUCK - 1 && t == 0) rowptr[NNODES] = MEDGES;
        __syncthreads();

        for (int i = t; i < cnt; i += 256) {
            int v = st[i];
            int dd = v >> 16;
            int r = atomicAdd(&fillc[dd], 1);
            esrc[ebase + dexcl[dd] + r] = v & 0xFFFF;
        }
        return;
    }

    // ---- gemm1: h1(fp16) = x @ W1 (+ fused alpha dots), f16 MFMA ----
    const int tid  = threadIdx.x;
    const int lane = tid & 63;
    const int wv   = tid >> 6;
    const int m    = lane & 15;
    const int quad = lane >> 4;
    const int node0 = (blockIdx.x - NBUCK) * 64;

    int arow = node0 + wv * 16 + m;
    if (arow >= NNODES) arow = NNODES - 1;
    const float* xr = x + (size_t)arow * FIN + quad * 8;

    const half8_t* Wp = (const half8_t*)W1p;

    f32x4 acc[6];
#pragma unroll
    for (int t = 0; t < 6; ++t) acc[t] = (f32x4){0.f, 0.f, 0.f, 0.f};

#pragma unroll
    for (int ks = 0; ks < 8; ++ks) {
        float4 v0 = *(const float4*)(xr + ks * 32);
        float4 v1 = *(const float4*)(xr + ks * 32 + 4);
        half8_t a;
        a[0] = (_Float16)v0.x; a[1] = (_Float16)v0.y;
        a[2] = (_Float16)v0.z; a[3] = (_Float16)v0.w;
        a[4] = (_Float16)v1.x; a[5] = (_Float16)v1.y;
        a[6] = (_Float16)v1.z; a[7] = (_Float16)v1.w;
#pragma unroll
        for (int t = 0; t < 6; ++t) {
            half8_t b = Wp[(t * 8 + ks) * 64 + lane];
            acc[t] = __builtin_amdgcn_mfma_f32_16x16x32_f16(a, b, acc[t], 0, 0, 0);
        }
    }

    float as_reg[6], ad_reg[6];
#pragma unroll
    for (int t = 0; t < 6; ++t) {
        as_reg[t] = a_src[t * 16 + m];
        ad_reg[t] = a_dst[t * 16 + m];
    }

#pragma unroll
    for (int r = 0; r < 4; ++r) {
        int node = node0 + wv * 16 + quad * 4 + r;
        float ps = 0.f, pd = 0.f;
#pragma unroll
        for (int t = 0; t < 6; ++t) {
            ps += acc[t][r] * as_reg[t];
            pd += acc[t][r] * ad_reg[t];
        }
#pragma unroll
        for (int off = 1; off < 16; off <<= 1) {
            ps += __shfl_xor(ps, off);
            pd += __shfl_xor(pd, off);
        }
        if (node < NNODES) {
            _Float16* hp = h1 + (size_t)node * 96 + m;
#pragma unroll
            for (int t = 0; t < 6; ++t) hp[t * 16] = (_Float16)acc[t][r];
            if (m == 0) { as1[node] = ps; ad1[node] = pd; }
        }
    }
}

// ---------------- Fused attn+agg layer 1 + gemm2 epilogue (round-2 loop, packed-f16 math) ----------------
// Half-wave (32 lanes) per node, 24 active lanes x uint2 = 4 fp16 feats/lane.
// sa.y holds alpha pre-packed as half2 (a,a): consume is 2 v_pk_fma_f16 per
// edge per lane (vs 8 scalar unpack+FMA with bf16) -> ~3x fewer VALU ops in
// the edge loop. W2 staged [k][c] untransposed: lane c -> bank c, 0 conflicts
// (verified r4/r5). Scheduling tricks absent: r3-r5 proved prefetch nulls here.

__global__ __launch_bounds__(256) void agg96g2_kernel(const _Float16* __restrict__ h,
                                                      const float* __restrict__ asrc,
                                                      const float* __restrict__ adst,
                                                      const float* __restrict__ bias,
                                                      const int* __restrict__ rowptr,
                                                      const int* __restrict__ esrc,
                                                      const float* __restrict__ W2,
                                                      const float* __restrict__ a2s,
                                                      const float* __restrict__ a2d,
                                                      uint32* __restrict__ h2b,
                                                      float* __restrict__ as2,
                                                      float* __restrict__ ad2) {
    __shared__ __align__(16) int2  sa[4][2][32];
    __shared__ __align__(16) float W2n[96 * 32];      // [k][c]: lane c -> bank c
    __shared__ __align__(16) float y_sh[4][2][96];

    // stage W2 first: barrier fires with nothing else in flight (r4 lesson)
    for (int idx = threadIdx.x; idx < 96 * 32; idx += 256)
        W2n[idx] = W2[idx];
    __syncthreads();

    const int wave = threadIdx.x >> 6;
    const int lane = threadIdx.x & 63;
    const int hf   = lane >> 5;
    const int fl32 = lane & 31;
    const int i = blockIdx.x * 8 + wave * 2 + hf;   // 50000 = 8*6250 exact

    const int start = rowptr[i];
    const int deg   = rowptr[i + 1] - start;
    const float ad  = adst[i];
    const float a2s_v = a2s[fl32];
    const float a2d_v = a2d[fl32];
    const int fl    = (fl32 < 24) ? fl32 : 23;

    half2_t acc01 = {(_Float16)0.f, (_Float16)0.f};
    half2_t acc23 = acc01;

    if (deg <= 32) {
        bool valid = fl32 < deg;
        int s_reg = valid ? esrc[start + fl32] : 0;
        float e = valid ? lrelu(asrc[s_reg] + ad) : -1e30f;
        float mx = e;
#pragma unroll
        for (int off = 16; off; off >>= 1) mx = fmaxf(mx, __shfl_xor(mx, off));
        float ex = valid ? __expf(e - mx) : 0.f;
        float sum = ex;
#pragma unroll
        for (int off = 16; off; off >>= 1) sum += __shfl_xor(sum, off);
        sa[wave][hf][fl32] = make_int2(s_reg, (int)h22u(bc2(ex / sum)));  // alpha half2 (0 for pads)

        const int4* sap = (const int4*)&sa[wave][hf][0];

        for (int eb = 0; eb < deg; eb += 8) {
            int4 qa = sap[(eb >> 1) + 0];
            int4 qb = sap[(eb >> 1) + 1];
            int4 qc = sap[(eb >> 1) + 2];
            int4 qd = sap[(eb >> 1) + 3];
            const uint2* r0 = (const uint2*)(h + (size_t)qa.x * 96);
            const uint2* r1 = (const uint2*)(h + (size_t)qa.z * 96);
            const uint2* r2 = (const uint2*)(h + (size_t)qb.x * 96);
            const uint2* r3 = (const uint2*)(h + (size_t)qb.z * 96);
            const uint2* r4 = (const uint2*)(h + (size_t)qc.x * 96);
            const uint2* r5 = (const uint2*)(h + (size_t)qc.z * 96);
            const uint2* r6 = (const uint2*)(h + (size_t)qd.x * 96);
            const uint2* r7 = (const uint2*)(h + (size_t)qd.z * 96);
            uint2 u0 = r0[fl], u1 = r1[fl], u2 = r2[fl], u3 = r3[fl];
            uint2 u4 = r4[fl], u5 = r5[fl], u6 = r6[fl], u7 = r7[fl];
            half2_t a0 = u2h2((uint32)qa.y), a1 = u2h2((uint32)qa.w);
            half2_t a2 = u2h2((uint32)qb.y), a3 = u2h2((uint32)qb.w);
            half2_t a4 = u2h2((uint32)qc.y), a5 = u2h2((uint32)qc.w);
            half2_t a6 = u2h2((uint32)qd.y), a7 = u2h2((uint32)qd.w);
            acc01 += a0 * u2h2(u0.x) + a1 * u2h2(u1.x) + a2 * u2h2(u2.x) + a3 * u2h2(u3.x)
                   + a4 * u2h2(u4.x) + a5 * u2h2(u5.x) + a6 * u2h2(u6.x) + a7 * u2h2(u7.x);
            acc23 += a0 * u2h2(u0.y) + a1 * u2h2(u1.y) + a2 * u2h2(u2.y) + a3 * u2h2(u3.y)
                   + a4 * u2h2(u4.y) + a5 * u2h2(u5.y) + a6 * u2h2(u6.y) + a7 * u2h2(u7.y);
        }
    } else {
        float mx = -1e30f;
        for (int p = start + fl32; p < start + deg; p += 32)
            mx = fmaxf(mx, lrelu(asrc[esrc[p]] + ad));
#pragma unroll
        for (int off = 16; off; off >>= 1) mx = fmaxf(mx, __shfl_xor(mx, off));
        float sum = 0.f;
        for (int p = start + fl32; p < start + deg; p += 32)
            sum += __expf(lrelu(asrc[esrc[p]] + ad) - mx);
#pragma unroll
        for (int off = 16; off; off >>= 1) sum += __shfl_xor(sum, off);
        float inv = 1.f / sum;
        for (int e = 0; e < deg; ++e) {
            int s = esrc[start + e];
            half2_t a = bc2(__expf(lrelu(asrc[s] + ad) - mx) * inv);
            uint2 u = ((const uint2*)(h + (size_t)s * 96))[fl];
            acc01 += a * u2h2(u.x);
            acc23 += a * u2h2(u.y);
        }
    }

    // ---- epilogue: bias + ELU -> y_sh, then fused h2 = y @ W2 (conflict-free W2n) ----
    if (fl32 < 24) {
        float* yp = &y_sh[wave][hf][4 * fl32];
        yp[0] = elu_fast((float)acc01[0] + bias[4 * fl32 + 0]);
        yp[1] = elu_fast((float)acc01[1] + bias[4 * fl32 + 1]);
        yp[2] = elu_fast((float)acc23[0] + bias[4 * fl32 + 2]);
        yp[3] = elu_fast((float)acc23[1] + bias[4 * fl32 + 3]);
    }
    asm volatile("s_waitcnt lgkmcnt(0)" ::: "memory");   // wave-internal y_sh visibility

    const float* yrow = &y_sh[wave][hf][0];
    float h2c = 0.f;
#pragma unroll
    for (int k4 = 0; k4 < 96; k4 += 4) {
        float4 yv = *(const float4*)(yrow + k4);       // broadcast within half
        h2c = fmaf(yv.x, W2n[(k4 + 0) * 32 + fl32], h2c);
        h2c = fmaf(yv.y, W2n[(k4 + 1) * 32 + fl32], h2c);
        h2c = fmaf(yv.z, W2n[(k4 + 2) * 32 + fl32], h2c);
        h2c = fmaf(yv.w, W2n[(k4 + 3) * 32 + fl32], h2c);
    }

    float ps = h2c * a2s_v;
    float pd = h2c * a2d_v;
#pragma unroll
    for (int off = 1; off < 32; off <<= 1) {        // reduce within 32-lane half
        ps += __shfl_xor(ps, off);
        pd += __shfl_xor(pd, off);
    }
    float partner = __shfl_xor(h2c, 16);            // class c+16 for c<16
    if (fl32 < 16)
        h2b[(size_t)i * 16 + fl32] = pack_h2(h2c, partner);
    if (fl32 == 0) { as2[i] = ps; ad2[i] = pd; }
}

// ---------------- Fused attn + aggregation layer 2 (packed-f16): TWO nodes per wave ----------------
// Half-wave per node; 4 groups x 8 lanes read 64 B h2b rows via dwordx2.
// h2b uint32 index m holds classes (m, m+16) as half2.

__global__ __launch_bounds__(256) void agg32_kernel(const uint32* __restrict__ h2b,
                                                    const float* __restrict__ asrc,
                                                    const float* __restrict__ adst,
                                                    const float* __restrict__ bias,
                                                    const int* __restrict__ rowptr,
                                                    const int* __restrict__ esrc,
                                                    float* __restrict__ out) {
    __shared__ int2 sa[4][2][32];
    const int wave = threadIdx.x >> 6;
    const int lane = threadIdx.x & 63;
    const int hf   = lane >> 5;
    const int fl32 = lane & 31;
    const int i = blockIdx.x * 8 + wave * 2 + hf;   // 6250 blocks exact

    const int start = rowptr[i];
    const int deg   = rowptr[i + 1] - start;
    const float ad  = adst[i];
    const int g  = fl32 >> 3;        // edge group 0..3 within half
    const int fl = fl32 & 7;         // uint2 index within row

    half2_t acc01 = {(_Float16)0.f, (_Float16)0.f};
    half2_t acc23 = acc01;

    if (deg <= 32) {
        bool valid = fl32 < deg;
        int s_reg = valid ? esrc[start + fl32] : 0;
        float e = valid ? lrelu(asrc[s_reg] + ad) : -1e30f;
        float mx = e;
#pragma unroll
        for (int off = 16; off; off >>= 1) mx = fmaxf(mx, __shfl_xor(mx, off));
        float ex = valid ? __expf(e - mx) : 0.f;
        float sum = ex;
#pragma unroll
        for (int off = 16; off; off >>= 1) sum += __shfl_xor(sum, off);
        sa[wave][hf][fl32] = make_int2(s_reg, (int)h22u(bc2(ex / sum)));

#pragma unroll 2
        for (int eb = 0; eb < deg; eb += 4) {
            int e0 = eb + g;
            int2 q = sa[wave][hf][(e0 < 32) ? e0 : 31];
            half2_t a = (e0 < deg) ? u2h2((uint32)q.y)
                                   : (half2_t){(_Float16)0.f, (_Float16)0.f};
            const uint2* hr = (const uint2*)(h2b + (size_t)q.x * 16);
            uint2 u = hr[fl];
            acc01 += a * u2h2(u.x);      // classes (2fl, 2fl+16)
            acc23 += a * u2h2(u.y);      // classes (2fl+1, 2fl+17)
        }
    } else {
        float mx = -1e30f;
        for (int p = start + fl32; p < start + deg; p += 32)
            mx = fmaxf(mx, lrelu(asrc[esrc[p]] + ad));
#pragma unroll
        for (int off = 16; off; off >>= 1) mx = fmaxf(mx, __shfl_xor(mx, off));
        float sum = 0.f;
        for (int p = start + fl32; p < start + deg; p += 32)
            sum += __expf(lrelu(asrc[esrc[p]] + ad) - mx);
#pragma unroll
        for (int off = 16; off; off >>= 1) sum += __shfl_xor(sum, off);
        float inv = 1.f / sum;
        for (int p = start + g; p < start + deg; p += 4) {
            int s = esrc[p];                          // 8 lanes same addr: broadcast
            half2_t a = bc2(__expf(lrelu(asrc[s] + ad) - mx) * inv);
            const uint2* hr = (const uint2*)(h2b + (size_t)s * 16);
            uint2 u = hr[fl];
            acc01 += a * u2h2(u.x);
            acc23 += a * u2h2(u.y);
        }
    }

    // reduce over the 4 groups within the half (packed adds via bit-shuffles)
#pragma unroll
    for (int j = 0; j < 2; ++j) {
        int sh = (j == 0) ? 8 : 16;
        acc01 += u2h2((uint32)__shfl_xor((int)h22u(acc01), sh));
        acc23 += u2h2((uint32)__shfl_xor((int)h22u(acc23), sh));
    }

    // log_softmax over 32 classes spread across lanes fl (8) x 4 values
    float z0 = (float)acc01[0] + bias[2 * fl];
    float z1 = (float)acc01[1] + bias[2 * fl + 16];
    float z2 = (float)acc23[0] + bias[2 * fl + 1];
    float z3 = (float)acc23[1] + bias[2 * fl + 17];
    float m2 = fmaxf(fmaxf(z0, z1), fmaxf(z2, z3));
#pragma unroll
    for (int off = 4; off; off >>= 1) m2 = fmaxf(m2, __shfl_xor(m2, off));
    float s2 = __expf(z0 - m2) + __expf(z1 - m2) + __expf(z2 - m2) + __expf(z3 - m2);
#pragma unroll
    for (int off = 4; off; off >>= 1) s2 += __shfl_xor(s2, off);
    float ls = m2 + __logf(s2);
    if (fl32 < 8) {
        float* op = out + (size_t)i * 32;
        op[2 * fl]      = z0 - ls;
        op[2 * fl + 16] = z1 - ls;
        op[2 * fl + 1]  = z2 - ls;
        op[2 * fl + 17] = z3 - ls;
    }
}

// ---------------- launch ----------------

extern "C" void kernel_launch(void* const* d_in, const int* in_sizes, int n_in,
                              void* d_out, int out_size, void* d_ws, size_t ws_size,
                              hipStream_t stream) {
    const float* x   = (const float*)d_in[0];
    const int*   ei  = (const int*)d_in[1];
    const float* W1  = (const float*)d_in[2];
    const float* a1s = (const float*)d_in[3];
    const float* a1d = (const float*)d_in[4];
    const float* b1  = (const float*)d_in[5];
    const float* W2  = (const float*)d_in[6];
    const float* a2s = (const float*)d_in[7];
    const float* a2d = (const float*)d_in[8];
    const float* b2  = (const float*)d_in[9];
    float* out = (float*)d_out;

    size_t off = 0;
    auto alloc = [&](size_t bytes) {
        void* p = (char*)d_ws + off;
        off += (bytes + 255) & ~(size_t)255;
        return p;
    };
    _Float16* h1  = (_Float16*)alloc((size_t)NNODES * HID * 2); // fp16, 9.6 MB
    uint32* h2b   = (uint32*)alloc((size_t)NNODES * 16 * 4);    // half2, 3.2 MB
    int*  staging = (int*)alloc((size_t)NBUCK * BCAP * 4);      // 4.8 MB
    float* as1    = (float*)alloc((size_t)NNODES * 4);
    float* ad1    = (float*)alloc((size_t)NNODES * 4);
    float* as2    = (float*)alloc((size_t)NNODES * 4);
    float* ad2    = (float*)alloc((size_t)NNODES * 4);
    int*   rowptr = (int*)alloc((size_t)(NNODES + 1) * 4);
    int*   esrc   = (int*)alloc((size_t)MEDGES * 4);
    _Float16* W1p = (_Float16*)alloc((size_t)6 * 8 * 64 * 8 * 2); // 48 KiB
    int*   gcount = (int*)alloc((size_t)NBUCK * 4);

    const int nbB1    = (MEDGES + 2047) / 2048;  // 416
    const int nbGemm  = (NNODES + 63) / 64;      // 782
    const int nbAggP  = NNODES / 8;              // 6250 (exact)

    packw_kernel<<<16, 256, 0, stream>>>(W1, W1p, gcount);
    bucket1_kernel<<<nbB1, 256, 0, stream>>>(ei, gcount, staging);
    // bucket2 (needs bucket1) overlapped with gemm1 (needs packw): independent
    b2gemm1_kernel<<<NBUCK + nbGemm, 256, 0, stream>>>(staging, gcount, rowptr, esrc,
                                                       x, W1p, a1s, a1d, h1, as1, ad1);
    // layer-1 agg + fused layer-2 GEMM
    agg96g2_kernel<<<nbAggP, 256, 0, stream>>>(h1, as1, ad1, b1, rowptr, esrc,
                                               W2, a2s, a2d, h2b, as2, ad2);
    agg32_kernel<<<nbAggP, 256, 0, stream>>>(h2b, as2, ad2, b2, rowptr, esrc, out);
}